// Round 6
// baseline (505.369 us; speedup 1.0000x reference)
//
#include <hip/hip_runtime.h>
#include <hip/hip_bf16.h>

typedef __attribute__((ext_vector_type(8))) short bf16x8;
typedef __attribute__((ext_vector_type(4))) float f32x4;
typedef __attribute__((ext_vector_type(4))) short s16x4;

__device__ __forceinline__ short f2bf(float f) {
  union { float f; unsigned u; } v; v.f = f;
  unsigned r = v.u + 0x7fffu + ((v.u >> 16) & 1u);
  return (short)(r >> 16);
}

__device__ __forceinline__ float bf2f(short s) {
  union { float f; unsigned u; } v; v.u = ((unsigned)(unsigned short)s) << 16;
  return v.f;
}

#define GLD_LDS(g, l) __builtin_amdgcn_global_load_lds( \
    (const __attribute__((address_space(1))) void*)(g), \
    (__attribute__((address_space(3))) void*)(l), 16, 0, 0)

// ---- x -> xb (bf16 row-major) + xbT (bf16 [b][c][n]) via tiled transpose ----
__global__ __launch_bounds__(256)
void convt_k(const float* __restrict__ x, short* __restrict__ xb,
             short* __restrict__ xbT) {
  __shared__ short tile[64][72];
  const int b = blockIdx.z;
  const int n0 = blockIdx.y * 64;
  const int c0 = blockIdx.x * 64;
  const int t = threadIdx.x;
  const int nl = t >> 4;
  const int c4 = (t & 15) << 2;
  const float* xp = x + ((size_t)b * 4096 + n0) * 1024 + c0;
#pragma unroll
  for (int i = 0; i < 4; ++i) {
    const int n = nl + 16 * i;
    const float4 v = *(const float4*)(xp + (size_t)n * 1024 + c4);
    s16x4 o;
    o[0] = f2bf(v.x); o[1] = f2bf(v.y); o[2] = f2bf(v.z); o[3] = f2bf(v.w);
    *(s16x4*)(&xb[((size_t)b * 4096 + n0 + n) * 1024 + c0 + c4]) = o;
    *(s16x4*)(&tile[n][c4]) = o;
  }
  __syncthreads();
  const int cll = t >> 4;
  const int n4 = (t & 15) << 2;
#pragma unroll
  for (int i = 0; i < 4; ++i) {
    const int c = cll + 16 * i;
    s16x4 o;
    o[0] = tile[n4 + 0][c]; o[1] = tile[n4 + 1][c];
    o[2] = tile[n4 + 2][c]; o[3] = tile[n4 + 3][c];
    *(s16x4*)(&xbT[((size_t)b * 1024 + c0 + c) * 4096 + n0 + n4]) = o;
  }
}

// ------- transpose + convert weights: Wt[d][c] = W[c][d] (+I for z<5; g-fold z==5) -------
__global__ void twc_k(const float* __restrict__ Wq, const float* __restrict__ Wk,
                      const float* __restrict__ Wv, const float* __restrict__ Wo,
                      const float* __restrict__ lng, short* __restrict__ dst) {
  __shared__ float tile[32][33];
  const int z = blockIdx.z;
  const float* src = (z == 0) ? Wq
                   : (z == 1) ? Wk
                   : (z == 2) ? (Wk + 1048576)
                   : (z == 3) ? Wv
                   : (z == 4) ? (Wv + 1048576)
                   : Wo;
  short* d = dst + (size_t)z * 1048576;
  const int tx = threadIdx.x, ty = threadIdx.y;
  const int c0 = blockIdx.y * 32, d0 = blockIdx.x * 32;
#pragma unroll
  for (int i = 0; i < 4; ++i)
    tile[ty + i * 8][tx] = src[(size_t)(c0 + ty + i * 8) * 1024 + d0 + tx];
  __syncthreads();
#pragma unroll
  for (int i = 0; i < 4; ++i) {
    const int cc = c0 + tx;
    const int dd = d0 + ty + i * 8;
    float v = tile[tx][ty + i * 8];
    if (z < 5) {
      if (cc == dd) v += 1.0f;  // fold residual: x + x@W = x@(I+W)
    } else {
      v *= lng[cc];             // fold LN gain into Wo
    }
    d[(size_t)dd * 1024 + cc] = f2bf(v);
  }
}

// ------- column sums of xb per batch: s[b][c] -------
__global__ __launch_bounds__(256)
void colsum_k(const short* __restrict__ xb, float* __restrict__ s) {
  const int b = blockIdx.y;
  const int cl = threadIdx.x & 63;
  const int c = blockIdx.x * 64 + cl;
  const int part = threadIdx.x >> 6;
  const short* p = xb + ((size_t)b << 22) + c;
  float acc = 0.f;
  for (int r = part; r < 4096; r += 4) acc += bf2f(p[(size_t)r << 10]);
  __shared__ float red[4][64];
  red[part][cl] = acc;
  __syncthreads();
  if (part == 0) s[b * 1024 + c] = red[0][cl] + red[1][cl] + red[2][cl] + red[3][cl];
}

// ------- u[k][b] = W~k^T s_b ; w[k][b] = W~v^T s_b -------
__global__ __launch_bounds__(256)
void gemv_k(const short* __restrict__ wt, const float* __restrict__ s,
            float* __restrict__ u, float* __restrict__ w) {
  const int z = blockIdx.z, b = blockIdx.y;
  const int lane = threadIdx.x & 63, wid = threadIdx.x >> 6;
  const short* W = wt + ((size_t)(z + 1) << 20);
  const float* sb = s + b * 1024;
  float* outp = (z < 2) ? (u + (z * 4 + b) * 1024) : (w + ((z - 2) * 4 + b) * 1024);
#pragma unroll 1
  for (int it = 0; it < 16; ++it) {
    const int d = blockIdx.x * 64 + wid * 16 + it;
    const short* row = W + (size_t)d * 1024 + lane * 16;
    float acc = 0.f;
#pragma unroll
    for (int j = 0; j < 16; ++j) acc += bf2f(row[j]) * sb[lane * 16 + j];
#pragma unroll
    for (int o = 32; o > 0; o >>= 1) acc += __shfl_down(acc, o);
    if (lane == 0) outp[d] = acc;
  }
}

// ---------------- 256x256-tile BK=32 4-buffer counted-vmcnt GEMM ----------------
// MODE 0: qproj   (A=xb, B=wt_q, out q bf16 + bq)
// MODE 1: gemmo   (A=oat, B=wt_o(g-folded), folded-LN fp32 epilogue)
// MODE 2: gram    (A=B=xbT_b, lda=4096, split-K=4, out Pg fp32 partials)
template <int MODE>
__global__ __launch_bounds__(512, 2)
void gemm256p_k(const short* __restrict__ A, const short* __restrict__ WT,
                const float* __restrict__ bq,
                const float* __restrict__ mu, const float* __restrict__ rstd,
                const float* __restrict__ uu, const float* __restrict__ tt,
                short* __restrict__ bout, float* __restrict__ fout) {
  extern __shared__ short lds[];  // 131072 B = 4 bufs x (8192 A + 8192 B shorts)
  const int tid = threadIdx.x;
  const int lane = tid & 63;
  const int wv = tid >> 6;   // 0..7
  const int wm = wv >> 2;    // 0..1
  const int wn = wv & 3;     // 0..3
  const int swz = ((blockIdx.x & 7) << 5) + (blockIdx.x >> 3);  // 256 blocks, XCD-bijective

  int bm0, bn0, ld, koff;
  const short *Ap, *Bp;
  float* po = fout;
  if (MODE == 2) {
    const int kz = swz & 3, tl = (swz >> 2) & 15, b = swz >> 6;
    bm0 = (tl >> 2) << 8; bn0 = (tl & 3) << 8;
    ld = 4096; koff = kz << 10;
    Ap = A + ((size_t)b << 22);
    Bp = Ap;
    po = fout + ((size_t)((kz << 2) + b) << 20);
  } else {
    bm0 = (swz & 63) << 8; bn0 = (swz >> 6) << 8;
    ld = 1024; koff = 0;
    Ap = A; Bp = WT;
  }

  // staging lane decomposition (pair-line layout, dest linear = lane*16B)
  const int lrow = ((lane >> 3) << 1) | ((lane >> 2) & 1);
  const int kc = ((lane & 3) ^ ((lane >> 3) & 3)) << 3;
  const int cl = lane & 15;
  const int khi = lane >> 4;

  f32x4 acc[8][4];
#pragma unroll
  for (int i = 0; i < 8; ++i)
#pragma unroll
    for (int j = 0; j < 4; ++j) acc[i][j] = f32x4{0.f, 0.f, 0.f, 0.f};

  auto stage = [&](int buf, int t) {
    const int k0 = koff + (t << 5) + kc;
    short* ab = lds + (buf << 14);
    short* bb = ab + 8192;
#pragma unroll
    for (int c = 0; c < 2; ++c) {
      const int un = wv * 2 + c;
      GLD_LDS(Ap + (size_t)(bm0 + (un << 4) + lrow) * ld + k0, ab + (un << 9));
      GLD_LDS(Bp + (size_t)(bn0 + (un << 4) + lrow) * ld + k0, bb + (un << 9));
    }
  };

  auto compute = [&](int buf) {
    const short* ab = lds + (buf << 14);
    const short* bb = ab + 8192;
    bf16x8 af[8], bfr[4];
#pragma unroll
    for (int i = 0; i < 8; ++i) {
      const int R = (wm << 7) + (i << 4) + cl;
      af[i] = *(const bf16x8*)(ab + (R << 5) + ((khi ^ ((R >> 1) & 3)) << 3));
    }
#pragma unroll
    for (int j = 0; j < 4; ++j) {
      const int C = (wn << 6) + (j << 4) + cl;
      bfr[j] = *(const bf16x8*)(bb + (C << 5) + ((khi ^ ((C >> 1) & 3)) << 3));
    }
#pragma unroll
    for (int i = 0; i < 8; ++i)
#pragma unroll
      for (int j = 0; j < 4; ++j)
        acc[i][j] = __builtin_amdgcn_mfma_f32_16x16x32_bf16(af[i], bfr[j], acc[i][j], 0, 0, 0);
  };

  stage(0, 0);
  stage(1, 1);
  asm volatile("s_waitcnt vmcnt(4)" ::: "memory");
  __builtin_amdgcn_s_barrier();
#pragma unroll 1
  for (int t = 0; t < 30; ++t) {
    stage((t + 2) & 3, t + 2);
    compute(t & 3);
    asm volatile("s_waitcnt vmcnt(4)" ::: "memory");
    __builtin_amdgcn_s_barrier();
  }
  compute(2);
  asm volatile("s_waitcnt vmcnt(0)" ::: "memory");
  __builtin_amdgcn_s_barrier();
  compute(3);

  if (MODE == 2) {
#pragma unroll
    for (int i = 0; i < 8; ++i)
#pragma unroll
      for (int j = 0; j < 4; ++j) {
        const int col = bn0 + (wn << 6) + (j << 4) + cl;
        const int rowb = bm0 + (wm << 7) + (i << 4) + (khi << 2);
#pragma unroll
        for (int r = 0; r < 4; ++r)
          po[(size_t)(rowb + r) * 1024 + col] = acc[i][j][r];
      }
  } else if (MODE == 1) {
#pragma unroll
    for (int i = 0; i < 8; ++i) {
      const int rowb = bm0 + (wm << 7) + (i << 4) + (khi << 2);
      const float4 m4 = *(const float4*)(mu + rowb);
      const float4 s4 = *(const float4*)(rstd + rowb);
#pragma unroll
      for (int j = 0; j < 4; ++j) {
        const int col = bn0 + (wn << 6) + (j << 4) + cl;
        const float uc = uu[col];
        const float tc = tt[col];
        po[(size_t)(rowb + 0) * 1024 + col] = s4.x * (acc[i][j][0] - m4.x * uc) + tc;
        po[(size_t)(rowb + 1) * 1024 + col] = s4.y * (acc[i][j][1] - m4.y * uc) + tc;
        po[(size_t)(rowb + 2) * 1024 + col] = s4.z * (acc[i][j][2] - m4.z * uc) + tc;
        po[(size_t)(rowb + 3) * 1024 + col] = s4.w * (acc[i][j][3] - m4.w * uc) + tc;
      }
    }
  } else {
#pragma unroll
    for (int i = 0; i < 8; ++i)
#pragma unroll
      for (int j = 0; j < 4; ++j) {
        const int col = bn0 + (wn << 6) + (j << 4) + cl;
        const int rowb = bm0 + (wm << 7) + (i << 4) + (khi << 2);
        const float bi = bq[col];
#pragma unroll
        for (int r = 0; r < 4; ++r)
          bout[(size_t)(rowb + r) * 1024 + col] = f2bf(acc[i][j][r] + bi);
      }
  }
}

// ------- G~[b] = (Pg[0]+Pg[1]+Pg[2]+Pg[3]) / 4096 -> bf16 -------
__global__ __launch_bounds__(256)
void greduce_k(const float* __restrict__ Pg, short* __restrict__ G) {
  const int b = blockIdx.x >> 10;
  const int local = ((blockIdx.x & 1023) << 10) + (threadIdx.x << 2);
  float4 a = {0.f, 0.f, 0.f, 0.f};
#pragma unroll
  for (int kz = 0; kz < 4; ++kz) {
    const float4 v = *(const float4*)(Pg + (((size_t)((kz << 2) + b)) << 20) + local);
    a.x += v.x; a.y += v.y; a.z += v.z; a.w += v.w;
  }
  const float sc = 1.0f / 4096.0f;
  s16x4 o;
  o[0] = f2bf(a.x * sc); o[1] = f2bf(a.y * sc);
  o[2] = f2bf(a.z * sc); o[3] = f2bf(a.w * sc);
  *(s16x4*)(G + ((size_t)b << 20) + local) = o;
}

// ------- stage-1: Tt[b][e'][c] = sum_c' wt_v[e'][c'] * G~[b][c][c'] (128^2 tiles) -------
__global__ __launch_bounds__(256)
void gemm128_k(const short* __restrict__ A, const short* __restrict__ Bt,
               short* __restrict__ out) {
  __shared__ short Ab[2][4096];
  __shared__ short Bb[2][4096];
  const int bid = blockIdx.x;
  const int swz = ((bid & 7) << 4) + (bid >> 3);  // 128 blocks, XCD-bijective
  const int bm0 = (swz >> 3) << 7;                // 0..1920
  const int bn0 = (swz & 7) << 7;                 // 0..896
  const short* Bp = Bt + ((size_t)blockIdx.y << 20);
  short* op = out + ((size_t)blockIdx.y << 21);
  const int tid = threadIdx.x, lane = tid & 63, wid = tid >> 6;
  const int wm = (wid >> 1) << 6, wn = (wid & 1) << 6;
  const int lrow = ((lane >> 3) << 1) | ((lane >> 2) & 1);
  const int kc = ((lane & 3) ^ ((lane >> 3) & 3)) << 3;
  const int cl = lane & 15, khi = lane >> 4;

  f32x4 acc[4][4];
#pragma unroll
  for (int i = 0; i < 4; ++i)
#pragma unroll
    for (int j = 0; j < 4; ++j) acc[i][j] = f32x4{0.f, 0.f, 0.f, 0.f};

  auto stage = [&](int buf, int t) {
    const int k0 = (t << 5) + kc;
#pragma unroll
    for (int c = 0; c < 2; ++c) {
      const int un = wid * 2 + c;  // 8 units x 16 rows
      GLD_LDS(A + (size_t)(bm0 + (un << 4) + lrow) * 1024 + k0, &Ab[buf][un << 9]);
      GLD_LDS(Bp + (size_t)(bn0 + (un << 4) + lrow) * 1024 + k0, &Bb[buf][un << 9]);
    }
  };

  stage(0, 0);
  __syncthreads();
#pragma unroll 1
  for (int t = 0; t < 32; ++t) {
    const int cur = t & 1;
    if (t < 31) stage(cur ^ 1, t + 1);
    const short* ab = Ab[cur];
    const short* bb = Bb[cur];
    bf16x8 af[4], bfr[4];
#pragma unroll
    for (int i = 0; i < 4; ++i) {
      const int R = wm + (i << 4) + cl;
      af[i] = *(const bf16x8*)(ab + (R << 5) + ((khi ^ ((R >> 1) & 3)) << 3));
    }
#pragma unroll
    for (int j = 0; j < 4; ++j) {
      const int C = wn + (j << 4) + cl;
      bfr[j] = *(const bf16x8*)(bb + (C << 5) + ((khi ^ ((C >> 1) & 3)) << 3));
    }
#pragma unroll
    for (int i = 0; i < 4; ++i)
#pragma unroll
      for (int j = 0; j < 4; ++j)
        acc[i][j] = __builtin_amdgcn_mfma_f32_16x16x32_bf16(af[i], bfr[j], acc[i][j], 0, 0, 0);
    __syncthreads();
  }

#pragma unroll
  for (int i = 0; i < 4; ++i)
#pragma unroll
    for (int j = 0; j < 4; ++j) {
      const int col = bn0 + wn + (j << 4) + cl;
      const int rowb = bm0 + wm + (i << 4) + (khi << 2);
#pragma unroll
      for (int r = 0; r < 4; ++r)
        op[(size_t)(rowb + r) * 1024 + col] = f2bf(acc[i][j][r]);
    }
}

// ------- stage-2: M[k][b][h][d][e] = sum_c wt_k[hd+d][c] * Tt[b][k*1024+he+e][c] -------
__global__ __launch_bounds__(256)
void states2_k(const short* __restrict__ wt, const short* __restrict__ Tt,
               float* __restrict__ M) {
  __shared__ short Al[64 * 40];
  __shared__ short Bl[64 * 40];
  const int h = blockIdx.x, b = blockIdx.y, k = blockIdx.z;
  const short* Ap = wt + ((size_t)(1 + k) << 20) + ((size_t)(h * 64) << 10);
  const short* Bp = Tt + ((size_t)b << 21) + ((size_t)(k * 1024 + h * 64) << 10);
  const int tid = threadIdx.x, lane = tid & 63, wid = tid >> 6;
  const int srow = tid >> 2, sch = (tid & 3) << 3;

  f32x4 acc[4];
#pragma unroll
  for (int j = 0; j < 4; ++j) acc[j] = f32x4{0.f, 0.f, 0.f, 0.f};

#pragma unroll 1
  for (int ns = 0; ns < 1024; ns += 32) {
    bf16x8 va = *(const bf16x8*)(Ap + ((size_t)srow << 10) + ns + sch);
    bf16x8 vb = *(const bf16x8*)(Bp + ((size_t)srow << 10) + ns + sch);
    __syncthreads();
    *(bf16x8*)(Al + srow * 40 + sch) = va;
    *(bf16x8*)(Bl + srow * 40 + sch) = vb;
    __syncthreads();
    bf16x8 a = *(const bf16x8*)(Al + (wid * 16 + (lane & 15)) * 40 + ((lane >> 4) << 3));
#pragma unroll
    for (int j = 0; j < 4; ++j) {
      bf16x8 bb = *(const bf16x8*)(Bl + (j * 16 + (lane & 15)) * 40 + ((lane >> 4) << 3));
      acc[j] = __builtin_amdgcn_mfma_f32_16x16x32_bf16(a, bb, acc[j], 0, 0, 0);
    }
  }
  const size_t mb = ((size_t)((k * 4 + b) * 16 + h)) << 12;
  const int r0 = wid * 16 + ((lane >> 4) << 2);
  const int cl = lane & 15;
#pragma unroll
  for (int j = 0; j < 4; ++j)
#pragma unroll
    for (int r = 0; r < 4; ++r)
      M[mb + (size_t)(r0 + r) * 64 + j * 16 + cl] = acc[j][r];
}

// ------- combine: stt[bh][e][d] = bf16( prod_k (M_k[d][e] + bias-corrections) ) -------
__global__ __launch_bounds__(256)
void combine_k(const float* __restrict__ M, const float* __restrict__ u,
               const float* __restrict__ w, const float* __restrict__ bk,
               const float* __restrict__ bv, short* __restrict__ stt) {
  const int bh = blockIdx.x;
  const int b = bh >> 4, h = bh & 15;
  const float invN = 1.0f / 4096.0f;
  for (int t = threadIdx.x; t < 4096; t += 256) {
    const int d = t >> 6, e = t & 63;
    float m[2];
#pragma unroll
    for (int k = 0; k < 2; ++k) {
      const float bkd = bk[k * 1024 + h * 64 + d];
      const float bve = bv[k * 1024 + h * 64 + e];
      const float ud = u[(k * 4 + b) * 1024 + h * 64 + d];
      const float we = w[(k * 4 + b) * 1024 + h * 64 + e];
      m[k] = M[(((size_t)((k * 4 + b) * 16 + h)) << 12) + t]
           + (ud * bve + bkd * we + 4096.f * bkd * bve) * invN;
    }
    stt[(bh << 12) + (e << 6) + d] = f2bf(m[0] * m[1]);
  }
}

// ------- u[d] = sum_c g[c]Wo[c,d];  t[d] = sum_c b[c]Wo[c,d] + bo[d] -------
__global__ __launch_bounds__(256)
void ut_k(const float* __restrict__ Wo, const float* __restrict__ lng,
          const float* __restrict__ lnb, const float* __restrict__ bo,
          float* __restrict__ u, float* __restrict__ t) {
  const int dl = threadIdx.x & 63;
  const int dd = blockIdx.x * 64 + dl;
  const int part = threadIdx.x >> 6;
  float su = 0.f, st = 0.f;
  for (int c = part * 256; c < part * 256 + 256; ++c) {
    const float w = Wo[(size_t)c * 1024 + dd];
    su += lng[c] * w;
    st += lnb[c] * w;
  }
  __shared__ float rs[4][64], rt[4][64];
  rs[part][dl] = su; rt[part][dl] = st;
  __syncthreads();
  if (part == 0) {
    su = rs[0][dl] + rs[1][dl] + rs[2][dl] + rs[3][dl];
    st = rt[0][dl] + rt[1][dl] + rt[2][dl] + rt[3][dl];
    u[dd] = su;
    t[dd] = st + bo[dd];
  }
}

// ---------------- out_att = q @ state per (b,h) -> bf16 ----------------
__global__ __launch_bounds__(256)
void attn_k(const short* __restrict__ q, const short* __restrict__ stt,
            short* __restrict__ oat) {
  __shared__ short Al[128 * 72];
  __shared__ short Bl[64 * 72];
  const int tid = threadIdx.x;
  const int lane = tid & 63;
  const int wid = tid >> 6;
  const int mc = blockIdx.x;
  const int bh = blockIdx.y;
  const int b = bh >> 4, h = bh & 15;
  const size_t qbase = ((size_t)(b * 4096 + mc * 128)) * 1024 + h * 64;
#pragma unroll
  for (int s = 0; s < 4; ++s) {
    const int idx = tid + s * 256;
    const int row = idx >> 3, cc = (idx & 7) << 3;
    *(bf16x8*)(Al + row * 72 + cc) = *(const bf16x8*)(q + qbase + (size_t)row * 1024 + cc);
  }
#pragma unroll
  for (int s = 0; s < 2; ++s) {
    const int idx = tid + s * 256;
    const int row = idx >> 3, cc = (idx & 7) << 3;
    *(bf16x8*)(Bl + row * 72 + cc) = *(const bf16x8*)(stt + (bh << 12) + (row << 6) + cc);
  }
  __syncthreads();
  f32x4 acc[2][4];
#pragma unroll
  for (int i = 0; i < 2; ++i)
#pragma unroll
    for (int j = 0; j < 4; ++j) acc[i][j] = f32x4{0.f, 0.f, 0.f, 0.f};
#pragma unroll
  for (int ks = 0; ks < 2; ++ks) {
    bf16x8 a0 = *(const bf16x8*)(Al + (wid * 32 + (lane & 15)) * 72 + ks * 32 + ((lane >> 4) << 3));
    bf16x8 a1 = *(const bf16x8*)(Al + (wid * 32 + 16 + (lane & 15)) * 72 + ks * 32 + ((lane >> 4) << 3));
#pragma unroll
    for (int j = 0; j < 4; ++j) {
      bf16x8 bb = *(const bf16x8*)(Bl + (j * 16 + (lane & 15)) * 72 + ks * 32 + ((lane >> 4) << 3));
      acc[0][j] = __builtin_amdgcn_mfma_f32_16x16x32_bf16(a0, bb, acc[0][j], 0, 0, 0);
      acc[1][j] = __builtin_amdgcn_mfma_f32_16x16x32_bf16(a1, bb, acc[1][j], 0, 0, 0);
    }
  }
  const int r0 = wid * 32 + ((lane >> 4) << 2);
  const int cl = lane & 15;
#pragma unroll
  for (int i = 0; i < 2; ++i)
#pragma unroll
    for (int j = 0; j < 4; ++j)
#pragma unroll
      for (int r = 0; r < 4; ++r) {
        const int row = b * 4096 + mc * 128 + r0 + i * 16 + r;
        oat[(size_t)row * 1024 + h * 64 + j * 16 + cl] = f2bf(acc[i][j][r]);
      }
}

// ---------------- per-row mean / rstd of bf16 oat ----------------
__global__ __launch_bounds__(256)
void stats_k(const short* __restrict__ oat, float* __restrict__ mu,
             float* __restrict__ rstd) {
  const int row = blockIdx.x;
  const int tid = threadIdx.x;
  const s16x4 v = ((const s16x4*)(oat + (size_t)row * 1024))[tid];
  const float f0 = bf2f(v[0]), f1 = bf2f(v[1]), f2 = bf2f(v[2]), f3 = bf2f(v[3]);
  float s = f0 + f1 + f2 + f3;
  float s2 = f0 * f0 + f1 * f1 + f2 * f2 + f3 * f3;
#pragma unroll
  for (int o = 32; o > 0; o >>= 1) {
    s += __shfl_down(s, o);
    s2 += __shfl_down(s2, o);
  }
  __shared__ float red[8];
  const int wid = tid >> 6, lane = tid & 63;
  if (lane == 0) { red[wid] = s; red[wid + 4] = s2; }
  __syncthreads();
  if (tid == 0) {
    const float ts = red[0] + red[1] + red[2] + red[3];
    const float ts2 = red[4] + red[5] + red[6] + red[7];
    const float m = ts * (1.0f / 1024.0f);
    const float var = ts2 * (1.0f / 1024.0f) - m * m;
    mu[row] = m;
    rstd[row] = rsqrtf(var + 1e-5f);
  }
}

extern "C" void kernel_launch(void* const* d_in, const int* in_sizes, int n_in,
                              void* d_out, int out_size, void* d_ws, size_t ws_size,
                              hipStream_t stream) {
  const float* x = (const float*)d_in[0];
  const float* Wq = (const float*)d_in[1];
  const float* bq = (const float*)d_in[2];
  const float* Wk = (const float*)d_in[3];
  const float* bk = (const float*)d_in[4];
  const float* Wv = (const float*)d_in[5];
  const float* bv = (const float*)d_in[6];
  const float* Wo = (const float*)d_in[7];
  const float* bo = (const float*)d_in[8];
  const float* lng = (const float*)d_in[9];
  const float* lnb = (const float*)d_in[10];

  char* ws = (char*)d_ws;
  short* xb = (short*)(ws + 0);             // 33.5MB  x bf16 row-major; reused as oat
  short* wt = (short*)(ws + 33554432);      // 12.6MB  6x (I+W)^T / g-folded Wo^T bf16
  short* q = (short*)(ws + 46137344);       // 33.5MB  q bf16
  short* xbT = (short*)(ws + 79691776);     // 33.5MB  x^T bf16 [b][c][n]
  short* Gt = (short*)(ws + 113246208);     //  8.0MB  Gram bf16 [b][1024][1024]
  short* Tt = (short*)(ws + 121634816);     // 16.8MB  stage-1 out bf16 [b][2048][1024]
  float* M = (float*)(ws + 138412032);      //  4.2MB  per-head states fp32
  short* stt = (short*)(ws + 142606336);    //  0.5MB  state^T bf16
  float* s = (float*)(ws + 143130624);      //  16KB   column sums
  float* u = (float*)(ws + 143147008);      //  32KB   W~k^T s
  float* w = (float*)(ws + 143179776);      //  32KB   W~v^T s
  float* uu = (float*)(ws + 143212544);     //   4KB
  float* tt = (float*)(ws + 143216640);     //   4KB
  float* mu = (float*)(ws + 143220736);     //  64KB
  float* rstd = (float*)(ws + 143286272);   //  64KB
  float* Pg = (float*)(ws + 143351808);     //  67MB   gram split-K partials fp32
  short* oat = xb;                          // out_att bf16 (xb dead after qproj/colsum)

  convt_k<<<dim3(16, 64, 4), 256, 0, stream>>>(x, xb, xbT);
  twc_k<<<dim3(32, 32, 6), dim3(32, 8), 0, stream>>>(Wq, Wk, Wv, Wo, lng, wt);
  colsum_k<<<dim3(16, 4), 256, 0, stream>>>(xb, s);
  gemv_k<<<dim3(16, 4, 4), 256, 0, stream>>>(wt, s, u, w);

  // Gram: Pg[kz][b] = xbT_b @ xbT_b^T over K-chunk kz
  gemm256p_k<2><<<256, 512, 131072, stream>>>(xbT, nullptr, nullptr, nullptr, nullptr,
                                              nullptr, nullptr, nullptr, Pg);
  greduce_k<<<4096, 256, 0, stream>>>(Pg, Gt);

  // q projection
  gemm256p_k<0><<<256, 512, 131072, stream>>>(xb, wt, bq, nullptr, nullptr,
                                              nullptr, nullptr, q, nullptr);

  // stage-1: Tt[b] = [wt_v0; wt_v1] (2048x1024) @ G~_b
  gemm128_k<<<dim3(128, 4), 256, 0, stream>>>(wt + 3145728, Gt, Tt);
  // stage-2: per-(k,b,h) 64x64 contractions
  states2_k<<<dim3(16, 4, 2), 256, 0, stream>>>(wt, Tt, M);
  combine_k<<<64, 256, 0, stream>>>(M, u, w, bk, bv, stt);

  ut_k<<<16, 256, 0, stream>>>(Wo, lng, lnb, bo, uu, tt);
  attn_k<<<dim3(32, 64), 256, 0, stream>>>(q, stt, oat);
  stats_k<<<16384, 256, 0, stream>>>(oat, mu, rstd);
  gemm256p_k<1><<<256, 512, 131072, stream>>>(oat, wt + 5242880, nullptr, mu, rstd,
                                              uu, tt, nullptr, (float*)d_out);
}

// Round 7
// 266.441 us; speedup vs baseline: 1.8967x; 1.8967x over previous
//
#include <hip/hip_runtime.h>
#include <hip/hip_bf16.h>

typedef __attribute__((ext_vector_type(8))) short bf16x8;
typedef __attribute__((ext_vector_type(4))) float f32x4;
typedef __attribute__((ext_vector_type(4))) short s16x4;

__device__ __forceinline__ short f2bf(float f) {
  union { float f; unsigned u; } v; v.f = f;
  unsigned r = v.u + 0x7fffu + ((v.u >> 16) & 1u);
  return (short)(r >> 16);
}

__device__ __forceinline__ float bf2f(short s) {
  union { float f; unsigned u; } v; v.u = ((unsigned)(unsigned short)s) << 16;
  return v.f;
}

#define GLD_LDS(g, l) __builtin_amdgcn_global_load_lds( \
    (const __attribute__((address_space(1))) void*)(g), \
    (__attribute__((address_space(3))) void*)(l), 16, 0, 0)

// ---- x -> xb (bf16 row-major) + xbT (bf16 [b][c][n]) via tiled transpose ----
__global__ __launch_bounds__(256)
void convt_k(const float* __restrict__ x, short* __restrict__ xb,
             short* __restrict__ xbT) {
  __shared__ short tile[64][72];
  const int b = blockIdx.z;
  const int n0 = blockIdx.y * 64;
  const int c0 = blockIdx.x * 64;
  const int t = threadIdx.x;
  const int nl = t >> 4;
  const int c4 = (t & 15) << 2;
  const float* xp = x + ((size_t)b * 4096 + n0) * 1024 + c0;
#pragma unroll
  for (int i = 0; i < 4; ++i) {
    const int n = nl + 16 * i;
    const float4 v = *(const float4*)(xp + (size_t)n * 1024 + c4);
    s16x4 o;
    o[0] = f2bf(v.x); o[1] = f2bf(v.y); o[2] = f2bf(v.z); o[3] = f2bf(v.w);
    *(s16x4*)(&xb[((size_t)b * 4096 + n0 + n) * 1024 + c0 + c4]) = o;
    *(s16x4*)(&tile[n][c4]) = o;
  }
  __syncthreads();
  const int cll = t >> 4;
  const int n4 = (t & 15) << 2;
#pragma unroll
  for (int i = 0; i < 4; ++i) {
    const int c = cll + 16 * i;
    s16x4 o;
    o[0] = tile[n4 + 0][c]; o[1] = tile[n4 + 1][c];
    o[2] = tile[n4 + 2][c]; o[3] = tile[n4 + 3][c];
    *(s16x4*)(&xbT[((size_t)b * 1024 + c0 + c) * 4096 + n0 + n4]) = o;
  }
}

// ------- transpose + convert weights: Wt[d][c] = W[c][d] (+I for z<5; g-fold z==5) -------
__global__ void twc_k(const float* __restrict__ Wq, const float* __restrict__ Wk,
                      const float* __restrict__ Wv, const float* __restrict__ Wo,
                      const float* __restrict__ lng, short* __restrict__ dst) {
  __shared__ float tile[32][33];
  const int z = blockIdx.z;
  const float* src = (z == 0) ? Wq
                   : (z == 1) ? Wk
                   : (z == 2) ? (Wk + 1048576)
                   : (z == 3) ? Wv
                   : (z == 4) ? (Wv + 1048576)
                   : Wo;
  short* d = dst + (size_t)z * 1048576;
  const int tx = threadIdx.x, ty = threadIdx.y;
  const int c0 = blockIdx.y * 32, d0 = blockIdx.x * 32;
#pragma unroll
  for (int i = 0; i < 4; ++i)
    tile[ty + i * 8][tx] = src[(size_t)(c0 + ty + i * 8) * 1024 + d0 + tx];
  __syncthreads();
#pragma unroll
  for (int i = 0; i < 4; ++i) {
    const int cc = c0 + tx;
    const int dd = d0 + ty + i * 8;
    float v = tile[tx][ty + i * 8];
    if (z < 5) {
      if (cc == dd) v += 1.0f;  // fold residual: x + x@W = x@(I+W)
    } else {
      v *= lng[cc];             // fold LN gain into Wo
    }
    d[(size_t)dd * 1024 + cc] = f2bf(v);
  }
}

// ------- column sums of x per batch from xbT (coalesced rows): s[b*1024+c] -------
__global__ __launch_bounds__(256)
void colsumT_k(const short* __restrict__ xbT, float* __restrict__ s) {
  const int row = blockIdx.x;  // b*1024 + c
  const int tid = threadIdx.x;
  const short* p = xbT + ((size_t)row << 12);
  float acc = 0.f;
#pragma unroll
  for (int it = 0; it < 2; ++it) {
    const bf16x8 v = *(const bf16x8*)(p + ((tid + it * 256) << 3));
#pragma unroll
    for (int j = 0; j < 8; ++j) acc += bf2f(v[j]);
  }
#pragma unroll
  for (int o = 32; o > 0; o >>= 1) acc += __shfl_down(acc, o);
  __shared__ float red[4];
  if ((tid & 63) == 0) red[tid >> 6] = acc;
  __syncthreads();
  if (tid == 0) s[row] = red[0] + red[1] + red[2] + red[3];
}

// ------- u[k][b] = W~k^T s_b ; w[k][b] = W~v^T s_b -------
__global__ __launch_bounds__(256)
void gemv_k(const short* __restrict__ wt, const float* __restrict__ s,
            float* __restrict__ u, float* __restrict__ w) {
  const int z = blockIdx.z, b = blockIdx.y;
  const int lane = threadIdx.x & 63, wid = threadIdx.x >> 6;
  const short* W = wt + ((size_t)(z + 1) << 20);
  const float* sb = s + b * 1024;
  float* outp = (z < 2) ? (u + (z * 4 + b) * 1024) : (w + ((z - 2) * 4 + b) * 1024);
#pragma unroll 1
  for (int it = 0; it < 16; ++it) {
    const int d = blockIdx.x * 64 + wid * 16 + it;
    const short* row = W + (size_t)d * 1024 + lane * 16;
    float acc = 0.f;
#pragma unroll
    for (int j = 0; j < 16; ++j) acc += bf2f(row[j]) * sb[lane * 16 + j];
#pragma unroll
    for (int o = 32; o > 0; o >>= 1) acc += __shfl_down(acc, o);
    if (lane == 0) outp[d] = acc;
  }
}

// ---------------- fused gram + qproj (512 blocks, 256 each) ----------------
// mode 0 (even blocks): gram  Pg[kz][b] = xbT_b chunk @ xbT_b chunk^T (fp32 partials)
// mode 1 (odd blocks):  qproj q = xb @ wt_q^T + bq (bf16)
// 256x256 tile, BK=32, 4-buffer counted-vmcnt pipeline, pair-line XOR LDS layout.
__global__ __launch_bounds__(512, 2)
void gramq_k(const short* __restrict__ xb, const short* __restrict__ xbT,
             const short* __restrict__ wtq, const float* __restrict__ bq,
             short* __restrict__ q, float* __restrict__ Pg) {
  extern __shared__ short lds[];  // 131072 B
  const int tid = threadIdx.x;
  const int lane = tid & 63;
  const int wv = tid >> 6;
  const int wm = wv >> 2;
  const int wn = wv & 3;
  const int mode = blockIdx.x & 1;
  const int id = blockIdx.x >> 1;                 // 0..255
  const int swz = ((id & 7) << 5) + (id >> 3);    // XCD-bijective on 256

  int bm0, bn0, ld, koff;
  const short *Ap, *Bp;
  float* po = nullptr;
  if (mode == 0) {
    const int kz = swz & 3, tl = (swz >> 2) & 15, b = swz >> 6;
    bm0 = (tl >> 2) << 8; bn0 = (tl & 3) << 8;
    ld = 4096; koff = kz << 10;
    Ap = xbT + ((size_t)b << 22);
    Bp = Ap;
    po = Pg + ((size_t)((kz << 2) + b) << 20);
  } else {
    bm0 = (swz & 63) << 8; bn0 = (swz >> 6) << 8;
    ld = 1024; koff = 0;
    Ap = xb; Bp = wtq;
  }

  const int lrow = ((lane >> 3) << 1) | ((lane >> 2) & 1);
  const int kc = ((lane & 3) ^ ((lane >> 3) & 3)) << 3;
  const int cl = lane & 15;
  const int khi = lane >> 4;

  f32x4 acc[8][4];
#pragma unroll
  for (int i = 0; i < 8; ++i)
#pragma unroll
    for (int j = 0; j < 4; ++j) acc[i][j] = f32x4{0.f, 0.f, 0.f, 0.f};

  auto stage = [&](int buf, int t) {
    const int k0 = koff + (t << 5) + kc;
    short* ab = lds + (buf << 14);
    short* bb = ab + 8192;
#pragma unroll
    for (int c = 0; c < 2; ++c) {
      const int un = wv * 2 + c;
      GLD_LDS(Ap + (size_t)(bm0 + (un << 4) + lrow) * ld + k0, ab + (un << 9));
      GLD_LDS(Bp + (size_t)(bn0 + (un << 4) + lrow) * ld + k0, bb + (un << 9));
    }
  };

  auto compute = [&](int buf) {
    const short* ab = lds + (buf << 14);
    const short* bb = ab + 8192;
    bf16x8 af[8], bfr[4];
#pragma unroll
    for (int i = 0; i < 8; ++i) {
      const int R = (wm << 7) + (i << 4) + cl;
      af[i] = *(const bf16x8*)(ab + (R << 5) + ((khi ^ ((R >> 1) & 3)) << 3));
    }
#pragma unroll
    for (int j = 0; j < 4; ++j) {
      const int C = (wn << 6) + (j << 4) + cl;
      bfr[j] = *(const bf16x8*)(bb + (C << 5) + ((khi ^ ((C >> 1) & 3)) << 3));
    }
#pragma unroll
    for (int i = 0; i < 8; ++i)
#pragma unroll
      for (int j = 0; j < 4; ++j)
        acc[i][j] = __builtin_amdgcn_mfma_f32_16x16x32_bf16(af[i], bfr[j], acc[i][j], 0, 0, 0);
  };

  stage(0, 0);
  stage(1, 1);
  asm volatile("s_waitcnt vmcnt(4)" ::: "memory");
  __builtin_amdgcn_s_barrier();
#pragma unroll 1
  for (int t = 0; t < 30; ++t) {
    stage((t + 2) & 3, t + 2);
    compute(t & 3);
    asm volatile("s_waitcnt vmcnt(4)" ::: "memory");
    __builtin_amdgcn_s_barrier();
  }
  compute(2);
  asm volatile("s_waitcnt vmcnt(0)" ::: "memory");
  __builtin_amdgcn_s_barrier();
  compute(3);

  if (mode == 0) {
#pragma unroll
    for (int i = 0; i < 8; ++i)
#pragma unroll
      for (int j = 0; j < 4; ++j) {
        const int col = bn0 + (wn << 6) + (j << 4) + cl;
        const int rowb = bm0 + (wm << 7) + (i << 4) + (khi << 2);
#pragma unroll
        for (int r = 0; r < 4; ++r)
          po[(size_t)(rowb + r) * 1024 + col] = acc[i][j][r];
      }
  } else {
#pragma unroll
    for (int i = 0; i < 8; ++i)
#pragma unroll
      for (int j = 0; j < 4; ++j) {
        const int col = bn0 + (wn << 6) + (j << 4) + cl;
        const int rowb = bm0 + (wm << 7) + (i << 4) + (khi << 2);
        const float bi = bq[col];
#pragma unroll
        for (int r = 0; r < 4; ++r)
          q[(size_t)(rowb + r) * 1024 + col] = f2bf(acc[i][j][r] + bi);
      }
  }
}

// ---------------- final GEMM with folded LayerNorm (256^2, 4-buf pipeline) ----------------
__global__ __launch_bounds__(512, 2)
void gemmo_k(const short* __restrict__ A, const short* __restrict__ WT,
             const float* __restrict__ mu, const float* __restrict__ rstd,
             const float* __restrict__ uu, const float* __restrict__ tt,
             float* __restrict__ fout) {
  extern __shared__ short lds[];
  const int tid = threadIdx.x;
  const int lane = tid & 63;
  const int wv = tid >> 6;
  const int wm = wv >> 2;
  const int wn = wv & 3;
  const int swz = ((blockIdx.x & 7) << 5) + (blockIdx.x >> 3);
  const int bm0 = (swz & 63) << 8;
  const int bn0 = (swz >> 6) << 8;

  const int lrow = ((lane >> 3) << 1) | ((lane >> 2) & 1);
  const int kc = ((lane & 3) ^ ((lane >> 3) & 3)) << 3;
  const int cl = lane & 15;
  const int khi = lane >> 4;

  f32x4 acc[8][4];
#pragma unroll
  for (int i = 0; i < 8; ++i)
#pragma unroll
    for (int j = 0; j < 4; ++j) acc[i][j] = f32x4{0.f, 0.f, 0.f, 0.f};

  auto stage = [&](int buf, int t) {
    const int k0 = (t << 5) + kc;
    short* ab = lds + (buf << 14);
    short* bb = ab + 8192;
#pragma unroll
    for (int c = 0; c < 2; ++c) {
      const int un = wv * 2 + c;
      GLD_LDS(A + (size_t)(bm0 + (un << 4) + lrow) * 1024 + k0, ab + (un << 9));
      GLD_LDS(WT + (size_t)(bn0 + (un << 4) + lrow) * 1024 + k0, bb + (un << 9));
    }
  };

  auto compute = [&](int buf) {
    const short* ab = lds + (buf << 14);
    const short* bb = ab + 8192;
    bf16x8 af[8], bfr[4];
#pragma unroll
    for (int i = 0; i < 8; ++i) {
      const int R = (wm << 7) + (i << 4) + cl;
      af[i] = *(const bf16x8*)(ab + (R << 5) + ((khi ^ ((R >> 1) & 3)) << 3));
    }
#pragma unroll
    for (int j = 0; j < 4; ++j) {
      const int C = (wn << 6) + (j << 4) + cl;
      bfr[j] = *(const bf16x8*)(bb + (C << 5) + ((khi ^ ((C >> 1) & 3)) << 3));
    }
#pragma unroll
    for (int i = 0; i < 8; ++i)
#pragma unroll
      for (int j = 0; j < 4; ++j)
        acc[i][j] = __builtin_amdgcn_mfma_f32_16x16x32_bf16(af[i], bfr[j], acc[i][j], 0, 0, 0);
  };

  stage(0, 0);
  stage(1, 1);
  asm volatile("s_waitcnt vmcnt(4)" ::: "memory");
  __builtin_amdgcn_s_barrier();
#pragma unroll 1
  for (int t = 0; t < 30; ++t) {
    stage((t + 2) & 3, t + 2);
    compute(t & 3);
    asm volatile("s_waitcnt vmcnt(4)" ::: "memory");
    __builtin_amdgcn_s_barrier();
  }
  compute(2);
  asm volatile("s_waitcnt vmcnt(0)" ::: "memory");
  __builtin_amdgcn_s_barrier();
  compute(3);

#pragma unroll
  for (int i = 0; i < 8; ++i) {
    const int rowb = bm0 + (wm << 7) + (i << 4) + (khi << 2);
    const float4 m4 = *(const float4*)(mu + rowb);
    const float4 s4 = *(const float4*)(rstd + rowb);
#pragma unroll
    for (int j = 0; j < 4; ++j) {
      const int col = bn0 + (wn << 6) + (j << 4) + cl;
      const float uc = uu[col];
      const float tc = tt[col];
      fout[(size_t)(rowb + 0) * 1024 + col] = s4.x * (acc[i][j][0] - m4.x * uc) + tc;
      fout[(size_t)(rowb + 1) * 1024 + col] = s4.y * (acc[i][j][1] - m4.y * uc) + tc;
      fout[(size_t)(rowb + 2) * 1024 + col] = s4.z * (acc[i][j][2] - m4.z * uc) + tc;
      fout[(size_t)(rowb + 3) * 1024 + col] = s4.w * (acc[i][j][3] - m4.w * uc) + tc;
    }
  }
}

// ------- G~[b] = (Pg[0]+Pg[1]+Pg[2]+Pg[3]) / 4096 -> bf16 -------
__global__ __launch_bounds__(256)
void greduce_k(const float* __restrict__ Pg, short* __restrict__ G) {
  const int b = blockIdx.x >> 10;
  const int local = ((blockIdx.x & 1023) << 10) + (threadIdx.x << 2);
  float4 a = {0.f, 0.f, 0.f, 0.f};
#pragma unroll
  for (int kz = 0; kz < 4; ++kz) {
    const float4 v = *(const float4*)(Pg + (((size_t)((kz << 2) + b)) << 20) + local);
    a.x += v.x; a.y += v.y; a.z += v.z; a.w += v.w;
  }
  const float sc = 1.0f / 4096.0f;
  s16x4 o;
  o[0] = f2bf(a.x * sc); o[1] = f2bf(a.y * sc);
  o[2] = f2bf(a.z * sc); o[3] = f2bf(a.w * sc);
  *(s16x4*)(G + ((size_t)b << 20) + local) = o;
}

// ------- stage-1: Tt[b][e'][c] = sum_c' wt_v[e'][c'] * G~[b][c][c'] (128^2 tiles) -------
__global__ __launch_bounds__(256)
void gemm128_k(const short* __restrict__ A, const short* __restrict__ Bt,
               short* __restrict__ out) {
  __shared__ short Ab[2][4096];
  __shared__ short Bb[2][4096];
  const int bid = blockIdx.x;
  const int swz = ((bid & 7) << 4) + (bid >> 3);  // 128 blocks, XCD-bijective
  const int bm0 = (swz >> 3) << 7;                // 0..1920
  const int bn0 = (swz & 7) << 7;                 // 0..896
  const short* Bp = Bt + ((size_t)blockIdx.y << 20);
  short* op = out + ((size_t)blockIdx.y << 21);
  const int tid = threadIdx.x, lane = tid & 63, wid = tid >> 6;
  const int wm = (wid >> 1) << 6, wn = (wid & 1) << 6;
  const int lrow = ((lane >> 3) << 1) | ((lane >> 2) & 1);
  const int kc = ((lane & 3) ^ ((lane >> 3) & 3)) << 3;
  const int cl = lane & 15, khi = lane >> 4;

  f32x4 acc[4][4];
#pragma unroll
  for (int i = 0; i < 4; ++i)
#pragma unroll
    for (int j = 0; j < 4; ++j) acc[i][j] = f32x4{0.f, 0.f, 0.f, 0.f};

  auto stage = [&](int buf, int t) {
    const int k0 = (t << 5) + kc;
#pragma unroll
    for (int c = 0; c < 2; ++c) {
      const int un = wid * 2 + c;
      GLD_LDS(A + (size_t)(bm0 + (un << 4) + lrow) * 1024 + k0, &Ab[buf][un << 9]);
      GLD_LDS(Bp + (size_t)(bn0 + (un << 4) + lrow) * 1024 + k0, &Bb[buf][un << 9]);
    }
  };

  stage(0, 0);
  __syncthreads();
#pragma unroll 1
  for (int t = 0; t < 32; ++t) {
    const int cur = t & 1;
    if (t < 31) stage(cur ^ 1, t + 1);
    const short* ab = Ab[cur];
    const short* bb = Bb[cur];
    bf16x8 af[4], bfr[4];
#pragma unroll
    for (int i = 0; i < 4; ++i) {
      const int R = wm + (i << 4) + cl;
      af[i] = *(const bf16x8*)(ab + (R << 5) + ((khi ^ ((R >> 1) & 3)) << 3));
    }
#pragma unroll
    for (int j = 0; j < 4; ++j) {
      const int C = wn + (j << 4) + cl;
      bfr[j] = *(const bf16x8*)(bb + (C << 5) + ((khi ^ ((C >> 1) & 3)) << 3));
    }
#pragma unroll
    for (int i = 0; i < 4; ++i)
#pragma unroll
      for (int j = 0; j < 4; ++j)
        acc[i][j] = __builtin_amdgcn_mfma_f32_16x16x32_bf16(af[i], bfr[j], acc[i][j], 0, 0, 0);
    __syncthreads();
  }

#pragma unroll
  for (int i = 0; i < 4; ++i)
#pragma unroll
    for (int j = 0; j < 4; ++j) {
      const int col = bn0 + wn + (j << 4) + cl;
      const int rowb = bm0 + wm + (i << 4) + (khi << 2);
#pragma unroll
      for (int r = 0; r < 4; ++r)
        op[(size_t)(rowb + r) * 1024 + col] = f2bf(acc[i][j][r]);
    }
}

// ------- stage-2: M[k][b][h][d][e] = sum_c wt_k[hd+d][c] * Tt[b][k*1024+he+e][c] -------
__global__ __launch_bounds__(256)
void states2_k(const short* __restrict__ wt, const short* __restrict__ Tt,
               float* __restrict__ M) {
  __shared__ short Al[64 * 40];
  __shared__ short Bl[64 * 40];
  const int h = blockIdx.x, b = blockIdx.y, k = blockIdx.z;
  const short* Ap = wt + ((size_t)(1 + k) << 20) + ((size_t)(h * 64) << 10);
  const short* Bp = Tt + ((size_t)b << 21) + ((size_t)(k * 1024 + h * 64) << 10);
  const int tid = threadIdx.x, lane = tid & 63, wid = tid >> 6;
  const int srow = tid >> 2, sch = (tid & 3) << 3;

  f32x4 acc[4];
#pragma unroll
  for (int j = 0; j < 4; ++j) acc[j] = f32x4{0.f, 0.f, 0.f, 0.f};

#pragma unroll 1
  for (int ns = 0; ns < 1024; ns += 32) {
    bf16x8 va = *(const bf16x8*)(Ap + ((size_t)srow << 10) + ns + sch);
    bf16x8 vb = *(const bf16x8*)(Bp + ((size_t)srow << 10) + ns + sch);
    __syncthreads();
    *(bf16x8*)(Al + srow * 40 + sch) = va;
    *(bf16x8*)(Bl + srow * 40 + sch) = vb;
    __syncthreads();
    bf16x8 a = *(const bf16x8*)(Al + (wid * 16 + (lane & 15)) * 40 + ((lane >> 4) << 3));
#pragma unroll
    for (int j = 0; j < 4; ++j) {
      bf16x8 bb = *(const bf16x8*)(Bl + (j * 16 + (lane & 15)) * 40 + ((lane >> 4) << 3));
      acc[j] = __builtin_amdgcn_mfma_f32_16x16x32_bf16(a, bb, acc[j], 0, 0, 0);
    }
  }
  const size_t mb = ((size_t)((k * 4 + b) * 16 + h)) << 12;
  const int r0 = wid * 16 + ((lane >> 4) << 2);
  const int cl = lane & 15;
#pragma unroll
  for (int j = 0; j < 4; ++j)
#pragma unroll
    for (int r = 0; r < 4; ++r)
      M[mb + (size_t)(r0 + r) * 64 + j * 16 + cl] = acc[j][r];
}

// ------- combine: stt[bh][e][d] = bf16( prod_k (M_k[d][e] + bias-corrections) ) -------
__global__ __launch_bounds__(256)
void combine_k(const float* __restrict__ M, const float* __restrict__ u,
               const float* __restrict__ w, const float* __restrict__ bk,
               const float* __restrict__ bv, short* __restrict__ stt) {
  const int bh = blockIdx.x;
  const int b = bh >> 4, h = bh & 15;
  const float invN = 1.0f / 4096.0f;
  for (int t = threadIdx.x; t < 4096; t += 256) {
    const int d = t >> 6, e = t & 63;
    float m[2];
#pragma unroll
    for (int k = 0; k < 2; ++k) {
      const float bkd = bk[k * 1024 + h * 64 + d];
      const float bve = bv[k * 1024 + h * 64 + e];
      const float ud = u[(k * 4 + b) * 1024 + h * 64 + d];
      const float we = w[(k * 4 + b) * 1024 + h * 64 + e];
      m[k] = M[(((size_t)((k * 4 + b) * 16 + h)) << 12) + t]
           + (ud * bve + bkd * we + 4096.f * bkd * bve) * invN;
    }
    stt[(bh << 12) + (e << 6) + d] = f2bf(m[0] * m[1]);
  }
}

// ------- u[d] = sum_c g[c]Wo[c,d];  t[d] = sum_c b[c]Wo[c,d] + bo[d] -------
__global__ __launch_bounds__(256)
void ut_k(const float* __restrict__ Wo, const float* __restrict__ lng,
          const float* __restrict__ lnb, const float* __restrict__ bo,
          float* __restrict__ u, float* __restrict__ t) {
  const int dl = threadIdx.x & 63;
  const int dd = blockIdx.x * 64 + dl;
  const int part = threadIdx.x >> 6;
  float su = 0.f, st = 0.f;
  for (int c = part * 256; c < part * 256 + 256; ++c) {
    const float w = Wo[(size_t)c * 1024 + dd];
    su += lng[c] * w;
    st += lnb[c] * w;
  }
  __shared__ float rs[4][64], rt[4][64];
  rs[part][dl] = su; rt[part][dl] = st;
  __syncthreads();
  if (part == 0) {
    su = rs[0][dl] + rs[1][dl] + rs[2][dl] + rs[3][dl];
    st = rt[0][dl] + rt[1][dl] + rt[2][dl] + rt[3][dl];
    u[dd] = su;
    t[dd] = st + bo[dd];
  }
}

// ---------------- out_att = q @ state per (b,h) -> bf16 ----------------
__global__ __launch_bounds__(256)
void attn_k(const short* __restrict__ q, const short* __restrict__ stt,
            short* __restrict__ oat) {
  __shared__ short Al[128 * 72];
  __shared__ short Bl[64 * 72];
  const int tid = threadIdx.x;
  const int lane = tid & 63;
  const int wid = tid >> 6;
  const int mc = blockIdx.x;
  const int bh = blockIdx.y;
  const int b = bh >> 4, h = bh & 15;
  const size_t qbase = ((size_t)(b * 4096 + mc * 128)) * 1024 + h * 64;
#pragma unroll
  for (int s = 0; s < 4; ++s) {
    const int idx = tid + s * 256;
    const int row = idx >> 3, cc = (idx & 7) << 3;
    *(bf16x8*)(Al + row * 72 + cc) = *(const bf16x8*)(q + qbase + (size_t)row * 1024 + cc);
  }
#pragma unroll
  for (int s = 0; s < 2; ++s) {
    const int idx = tid + s * 256;
    const int row = idx >> 3, cc = (idx & 7) << 3;
    *(bf16x8*)(Bl + row * 72 + cc) = *(const bf16x8*)(stt + (bh << 12) + (row << 6) + cc);
  }
  __syncthreads();
  f32x4 acc[2][4];
#pragma unroll
  for (int i = 0; i < 2; ++i)
#pragma unroll
    for (int j = 0; j < 4; ++j) acc[i][j] = f32x4{0.f, 0.f, 0.f, 0.f};
#pragma unroll
  for (int ks = 0; ks < 2; ++ks) {
    bf16x8 a0 = *(const bf16x8*)(Al + (wid * 32 + (lane & 15)) * 72 + ks * 32 + ((lane >> 4) << 3));
    bf16x8 a1 = *(const bf16x8*)(Al + (wid * 32 + 16 + (lane & 15)) * 72 + ks * 32 + ((lane >> 4) << 3));
#pragma unroll
    for (int j = 0; j < 4; ++j) {
      bf16x8 bb = *(const bf16x8*)(Bl + (j * 16 + (lane & 15)) * 72 + ks * 32 + ((lane >> 4) << 3));
      acc[0][j] = __builtin_amdgcn_mfma_f32_16x16x32_bf16(a0, bb, acc[0][j], 0, 0, 0);
      acc[1][j] = __builtin_amdgcn_mfma_f32_16x16x32_bf16(a1, bb, acc[1][j], 0, 0, 0);
    }
  }
  const int r0 = wid * 32 + ((lane >> 4) << 2);
  const int cl = lane & 15;
#pragma unroll
  for (int i = 0; i < 2; ++i)
#pragma unroll
    for (int j = 0; j < 4; ++j)
#pragma unroll
      for (int r = 0; r < 4; ++r) {
        const int row = b * 4096 + mc * 128 + r0 + i * 16 + r;
        oat[(size_t)row * 1024 + h * 64 + j * 16 + cl] = f2bf(acc[i][j][r]);
      }
}

// ---------------- per-row mean / rstd of bf16 oat ----------------
__global__ __launch_bounds__(256)
void stats_k(const short* __restrict__ oat, float* __restrict__ mu,
             float* __restrict__ rstd) {
  const int row = blockIdx.x;
  const int tid = threadIdx.x;
  const s16x4 v = ((const s16x4*)(oat + (size_t)row * 1024))[tid];
  const float f0 = bf2f(v[0]), f1 = bf2f(v[1]), f2 = bf2f(v[2]), f3 = bf2f(v[3]);
  float s = f0 + f1 + f2 + f3;
  float s2 = f0 * f0 + f1 * f1 + f2 * f2 + f3 * f3;
#pragma unroll
  for (int o = 32; o > 0; o >>= 1) {
    s += __shfl_down(s, o);
    s2 += __shfl_down(s2, o);
  }
  __shared__ float red[8];
  const int wid = tid >> 6, lane = tid & 63;
  if (lane == 0) { red[wid] = s; red[wid + 4] = s2; }
  __syncthreads();
  if (tid == 0) {
    const float ts = red[0] + red[1] + red[2] + red[3];
    const float ts2 = red[4] + red[5] + red[6] + red[7];
    const float m = ts * (1.0f / 1024.0f);
    const float var = ts2 * (1.0f / 1024.0f) - m * m;
    mu[row] = m;
    rstd[row] = rsqrtf(var + 1e-5f);
  }
}

extern "C" void kernel_launch(void* const* d_in, const int* in_sizes, int n_in,
                              void* d_out, int out_size, void* d_ws, size_t ws_size,
                              hipStream_t stream) {
  const float* x = (const float*)d_in[0];
  const float* Wq = (const float*)d_in[1];
  const float* bq = (const float*)d_in[2];
  const float* Wk = (const float*)d_in[3];
  const float* bk = (const float*)d_in[4];
  const float* Wv = (const float*)d_in[5];
  const float* bv = (const float*)d_in[6];
  const float* Wo = (const float*)d_in[7];
  const float* bo = (const float*)d_in[8];
  const float* lng = (const float*)d_in[9];
  const float* lnb = (const float*)d_in[10];

  char* ws = (char*)d_ws;
  short* xb = (short*)(ws + 0);             // 33.5MB  x bf16 row-major; reused as oat
  short* wt = (short*)(ws + 33554432);      // 12.6MB  6x (I+W)^T / g-folded Wo^T bf16
  short* q = (short*)(ws + 46137344);       // 33.5MB  q bf16
  short* xbT = (short*)(ws + 79691776);     // 33.5MB  x^T bf16 [b][c][n]
  short* Gt = (short*)(ws + 113246208);     //  8.0MB  Gram bf16 [b][1024][1024]
  short* Tt = (short*)(ws + 121634816);     // 16.8MB  stage-1 out bf16 [b][2048][1024]
  float* M = (float*)(ws + 138412032);      //  4.2MB  per-head states fp32
  short* stt = (short*)(ws + 142606336);    //  0.5MB  state^T bf16
  float* s = (float*)(ws + 143130624);      //  16KB   column sums
  float* u = (float*)(ws + 143147008);      //  32KB   W~k^T s
  float* w = (float*)(ws + 143179776);      //  32KB   W~v^T s
  float* uu = (float*)(ws + 143212544);     //   4KB
  float* tt = (float*)(ws + 143216640);     //   4KB
  float* mu = (float*)(ws + 143220736);     //  64KB
  float* rstd = (float*)(ws + 143286272);   //  64KB
  float* Pg = (float*)(ws + 143351808);     //  67MB   gram split-K partials fp32
  short* oat = xb;                          // out_att bf16 (xb dead after gram+qproj)

  convt_k<<<dim3(16, 64, 4), 256, 0, stream>>>(x, xb, xbT);
  twc_k<<<dim3(32, 32, 6), dim3(32, 8), 0, stream>>>(Wq, Wk, Wv, Wo, lng, wt);
  colsumT_k<<<4096, 256, 0, stream>>>(xbT, s);
  gemv_k<<<dim3(16, 4, 4), 256, 0, stream>>>(wt, s, u, w);

  // fused: Gram partials (even blocks) + q projection (odd blocks)
  gramq_k<<<512, 512, 131072, stream>>>(xb, xbT, wt, bq, q, Pg);
  greduce_k<<<4096, 256, 0, stream>>>(Pg, Gt);

  // stage-1: Tt[b] = [wt_v0; wt_v1] (2048x1024) @ G~_b
  gemm128_k<<<dim3(128, 4), 256, 0, stream>>>(wt + 3145728, Gt, Tt);
  // stage-2: per-(k,b,h) 64x64 contractions
  states2_k<<<dim3(16, 4, 2), 256, 0, stream>>>(wt, Tt, M);
  combine_k<<<64, 256, 0, stream>>>(M, u, w, bk, bv, stt);

  ut_k<<<16, 256, 0, stream>>>(Wo, lng, lnb, bo, uu, tt);
  attn_k<<<dim3(32, 64), 256, 0, stream>>>(q, stt, oat);
  stats_k<<<16384, 256, 0, stream>>>(oat, mu, rstd);
  gemmo_k<<<256, 512, 131072, stream>>>(oat, wt + 5242880, mu, rstd, uu, tt,
                                        (float*)d_out);
}